// Round 1
// baseline (1255.487 us; speedup 1.0000x reference)
//
#include <hip/hip_runtime.h>
#include <math.h>

constexpr int WID  = 320;
constexpr int HWc  = 320 * 320;        // 102400
constexpr int NIMG = 16;
constexpr int NSL  = 32;               // B*C slices for TV/DWT
constexpr int NTOT = NIMG * 2 * HWc;   // 3276800 floats per full array
constexpr float LAM_TV  = 0.005f;
constexpr float LAM_WAV = 0.005f;

__device__ __forceinline__ float softt(float v) {
    float a = fmaxf(fabsf(v) - LAM_WAV, 0.f);
    return copysignf(a, v);
}

// raw v_rsq_f32: ~1ulp, single instruction (rsqrtf can lower to the precise
// ocml multi-instruction path).
__device__ __forceinline__ float fast_rsq(float x) {
    float r;
    asm volatile("v_rsq_f32 %0, %1" : "=v"(r) : "v"(x));
    return r;
}

// ================= 320-point FFT core ======================================
// 320 = 5 (register DFT) x 64 (lane FFT via shfl_xor). Centered transform via
// (-1)^n modulation at load and (-1)^k at store (handled by callers).
// LESSONS: (R3,R6) wave-supply-bound — never trade wave count for ILP.
// (R10) DS shuffles overlap VALU at >=4 waves/SIMD — do NOT convert to DPP.
// (R11) twiddles from a 3.5KB L1-hot table, not __sincosf.
struct Tw { float tc, ts; float stc[6], sts[6]; };

// table layout: tb[(field)*64 + lane], fields: 0=tc 1=ts 2..7=stc 8..13=sts
__global__ void build_tw(float* tb) {
    const int lane = threadIdx.x;   // 64 threads
#pragma unroll
    for (int g = 0; g < 2; g++) {
        const float sgn = g ? 1.f : -1.f;
        float* p = tb + g * 14 * 64;
        float ts, tc;
        __sincosf(sgn * 6.283185307179586f * (float)lane / 320.f, &ts, &tc);
        p[lane] = tc; p[64 + lane] = ts;
#pragma unroll
        for (int s = 0; s < 6; s++) {
            int h = 32 >> s;
            int j = lane & (h - 1);
            float ang = sgn * 3.14159265358979323f * (float)j / (float)h;
            float ss, cc;
            __sincosf(ang, &ss, &cc);
            p[(2 + s) * 64 + lane] = cc;
            p[(8 + s) * 64 + lane] = ss;
        }
    }
}

__device__ __forceinline__ Tw load_tw(const float* __restrict__ tb, int lane) {
    Tw tw;
    tw.tc = tb[lane];
    tw.ts = tb[64 + lane];
#pragma unroll
    for (int s = 0; s < 6; s++) {
        tw.stc[s] = tb[(2 + s) * 64 + lane];
        tw.sts[s] = tb[(8 + s) * 64 + lane];
    }
    return tw;
}

// vr/vi hold elements n = lane + 64m (already sign-modulated).
// out: Cr/Ci hold X[5*bitrev6(lane) + k] in slot k (unscaled).
template<int SGN>
__device__ __forceinline__ void fft320_core(const float (&vr)[5], const float (&vi)[5],
                                            float (&Cr)[5], float (&Ci)[5],
                                            const Tw& tw, int lane) {
    const float cw1 = 0.30901699437494745f, sw1 = 0.9510565162951535f;
    const float cw2 = -0.8090169943749475f, sw2 = 0.5877852522924731f;
    const float cwt[5] = {1.f, cw1, cw2, cw2, cw1};
    const float swt[5] = {0.f, sw1, sw2, -sw2, -sw1};
    Cr[0] = vr[0] + vr[1] + vr[2] + vr[3] + vr[4];
    Ci[0] = vi[0] + vi[1] + vi[2] + vi[3] + vi[4];
#pragma unroll
    for (int k = 1; k < 5; k++) {
        float ar = vr[0], ai = vi[0];
#pragma unroll
        for (int m = 1; m < 5; m++) {
            int j = (m * k) % 5;
            float wr_ = cwt[j], wi_ = (float)SGN * swt[j];
            ar += vr[m] * wr_ - vi[m] * wi_;
            ai += vr[m] * wi_ + vi[m] * wr_;
        }
        Cr[k] = ar; Ci[k] = ai;
    }
    // twiddle W_320^{lane*k}
    float twr = 1.f, twi = 0.f;
#pragma unroll
    for (int k = 1; k < 5; k++) {
        float nr = twr * tw.tc - twi * tw.ts;
        twi = twr * tw.ts + twi * tw.tc;
        twr = nr;
        float r = Cr[k] * twr - Ci[k] * twi;
        Ci[k]   = Cr[k] * twi + Ci[k] * twr;
        Cr[k]   = r;
    }
    // 6-stage radix-2 DIF across 64 lanes
#pragma unroll
    for (int s = 0; s < 6; s++) {
        int h = 32 >> s;
        bool up = (lane & h) != 0;
#pragma unroll
        for (int k = 0; k < 5; k++) {
            float orr = __shfl_xor(Cr[k], h);
            float oii = __shfl_xor(Ci[k], h);
            if (up) {
                float dr = orr - Cr[k], di = oii - Ci[k];
                Cr[k] = dr * tw.stc[s] - di * tw.sts[s];
                Ci[k] = dr * tw.sts[s] + di * tw.stc[s];
            } else {
                Cr[k] += orr;
                Ci[k] += oii;
            }
        }
    }
}

// ---------------- row FFT pass (1 line/wave, 5120 waves = 5/SIMD) -----------
// EPI: 0 = plain store
//      2 = residual store: out = aux1 - val   (aux1 = z, PREFETCHED at entry)
//      3 = dual store:     out and out2 both get val
template<int SGN, int EPI>
__global__ __launch_bounds__(256) void fft_row(const float* __restrict__ in,
                                               float* __restrict__ out,
                                               const float* __restrict__ aux1,
                                               float* __restrict__ out2,
                                               const float* __restrict__ twb) {
    const int lane = threadIdx.x & 63;
    const int wv   = threadIdx.x >> 6;
    const int L    = blockIdx.x * 4 + wv;
    const int img  = L / 320;
    const int l    = L - img * 320;
    const size_t ibase = (size_t)img * 2 * HWc;
    const float* pre = in + ibase + (size_t)l * WID;
    const float* pim = pre + HWc;
    const int k1 = (int)(__brev((unsigned)lane) >> 26);   // bitrev6

    Tw tw = load_tw(twb, lane);   // L1-hot, issues before/with input loads

    float vr[5], vi[5];
    const float sgn_in = (lane & 1) ? -1.f : 1.f;
#pragma unroll
    for (int m = 0; m < 5; m++) {
        int n = lane + 64 * m;
        vr[m] = sgn_in * pre[n];
        vi[m] = sgn_in * pim[n];
    }
    // prefetch residual operand (z) before the latency-heavy core
    float zr[5], zi[5];
    if (EPI == 2) {
#pragma unroll
        for (int k = 0; k < 5; k++) {
            int idxs = 5 * k1 + k + l * WID;
            zr[k] = aux1[ibase + idxs];
            zi[k] = aux1[ibase + HWc + idxs];
        }
    }

    float Cr[5], Ci[5];
    fft320_core<SGN>(vr, vi, Cr, Ci, tw, lane);

    float* qre = out + ibase + (size_t)l * WID;
    float* qim = qre + HWc;
    const float scale = 0.05590169943749474f;  // 1/sqrt(320)
#pragma unroll
    for (int k = 0; k < 5; k++) {
        int kout = 5 * k1 + k;
        float s2 = (kout & 1) ? -scale : scale;
        float re = s2 * Cr[k];
        float im = s2 * Ci[k];
        const int idxs = kout + l * WID;
        if (EPI == 2) {
            re = zr[k] - re;
            im = zi[k] - im;
        }
        qre[kout] = re;
        qim[kout] = im;
        if (EPI == 3) {
            out2[ibase + idxs]       = re;
            out2[ibase + HWc + idxs] = im;
        }
    }
}

// ---------------- fused column FFT kernel (LDS-transposed, high-TLP) --------
// Block = 512 threads (8 waves) handles 8 complex columns; ONE column line
// per wave per pass -> 640 blocks x 8 = 5120 waves (5/SIMD).
// Tile [comp][row 320][9]: stride 9, gcd(9,32)=1 -> 2-way LDS aliasing (free).
// MODE 0: single inverse column FFT (init path).
// MODE 1: forward col FFT + k-space DC (m*(m*K - y)) + inverse col FFT.
constexpr int CB   = 8;        // columns per block
constexpr int CPAD = CB + 1;   // 9

template<int SGN>
__device__ __forceinline__ void fft_line_lds(float (*tile)[320][CPAD], int cl,
                                             int lane, const Tw& tw) {
    float vr[5], vi[5], Cr[5], Ci[5];
    const float sgn_in = (lane & 1) ? -1.f : 1.f;
#pragma unroll
    for (int m = 0; m < 5; m++) {
        int n = lane + 64 * m;
        vr[m] = sgn_in * tile[0][n][cl];
        vi[m] = sgn_in * tile[1][n][cl];
    }
    fft320_core<SGN>(vr, vi, Cr, Ci, tw, lane);
    const int k1 = (int)(__brev((unsigned)lane) >> 26);
    const float scale = 0.05590169943749474f;
#pragma unroll
    for (int k = 0; k < 5; k++) {
        int kout = 5 * k1 + k;
        float s2 = (kout & 1) ? -scale : scale;
        tile[0][kout][cl] = s2 * Cr[k];
        tile[1][kout][cl] = s2 * Ci[k];
    }
}

template<int MODE>
__global__ __launch_bounds__(512) void fft_col(const float* __restrict__ in,
                                               float* __restrict__ out,
                                               const float* __restrict__ y,
                                               const float* __restrict__ mask,
                                               const float* __restrict__ twb) {
    __shared__ float tile[2][320][CPAD];   // 23 KB
    const int tid = threadIdx.x;
    const int bpi = WID / CB;              // 40 blocks per image
    const int img = blockIdx.x / bpi;
    const int c0  = (blockIdx.x - img * bpi) * CB;
    const size_t ibase = (size_t)img * 2 * HWc;
    constexpr int C4 = CB / 4;             // 2 float4 groups per row
    constexpr int NE = 320 * C4;           // 640 float4 per component

#pragma unroll
    for (int comp = 0; comp < 2; comp++) {
        const float* p = in + ibase + (size_t)comp * HWc + c0;
        for (int i = tid; i < NE; i += 512) {
            int row = i >> 1, cg = (i & 1) << 2;
            float4 v = *(const float4*)(p + row * WID + cg);
            float* t = &tile[comp][row][cg];
            t[0] = v.x; t[1] = v.y; t[2] = v.z; t[3] = v.w;
        }
    }
    __syncthreads();

    const int lane = tid & 63;
    const int wv   = tid >> 6;             // wave = column index [0,8)

    if (MODE == 1) {
        Tw twf = load_tw(twb, lane);              // forward table
        fft_line_lds<-1>(tile, wv, lane, twf);
        __syncthreads();
        // k-space data consistency, all streams coalesced
        const float* pm  = mask + (size_t)img * HWc + c0;
        const float* pyr = y + ibase + c0;
        const float* pyi = y + ibase + HWc + c0;
        for (int i = tid; i < NE; i += 512) {
            int row = i >> 1, cg = (i & 1) << 2;
            float4 m4 = *(const float4*)(pm  + row * WID + cg);
            float4 yr = *(const float4*)(pyr + row * WID + cg);
            float4 yi = *(const float4*)(pyi + row * WID + cg);
            float* tr = &tile[0][row][cg];
            float* ti = &tile[1][row][cg];
            tr[0] = m4.x * (m4.x * tr[0] - yr.x);
            tr[1] = m4.y * (m4.y * tr[1] - yr.y);
            tr[2] = m4.z * (m4.z * tr[2] - yr.z);
            tr[3] = m4.w * (m4.w * tr[3] - yr.w);
            ti[0] = m4.x * (m4.x * ti[0] - yi.x);
            ti[1] = m4.y * (m4.y * ti[1] - yi.y);
            ti[2] = m4.z * (m4.z * ti[2] - yi.z);
            ti[3] = m4.w * (m4.w * ti[3] - yi.w);
        }
        __syncthreads();
    }
    {
        Tw twi = load_tw(twb + 14 * 64, lane);    // inverse table
        fft_line_lds<1>(tile, wv, lane, twi);
    }
    __syncthreads();
#pragma unroll
    for (int comp = 0; comp < 2; comp++) {
        float* p = out + ibase + (size_t)comp * HWc + c0;
        for (int i = tid; i < NE; i += 512) {
            int row = i >> 1, cg = (i & 1) << 2;
            const float* t = &tile[comp][row][cg];
            *(float4*)(p + row * WID + cg) = make_float4(t[0], t[1], t[2], t[3]);
        }
    }
}

// ============ fused TV prox + 3-level Haar shrinkage + FISTA ================
// R13: CROSS-WAVE EXACT TV. Block = 4 waves covers a 32-row x 48-col interior
// tile. Waves exchange the single boundary row values (py downward, u upward)
// through a 2KB LDS buffer each dual iteration (2 convergent barriers/iter,
// 11 total). Vertical halo now exists only at BLOCK boundaries: waves 0/3
// carry 12 rows (8 interior + 4 halo), waves 1/2 carry exactly their 8
// interior rows. Average rows/wave drops 16 -> 10 (1.6x less VALU+DS work),
// and wave-boundary rows become EXACT (previously halo-approximate), so
// numerics strictly improve. Interior strips stay Haar-8-aligned so the
// wavelet/FISTA epilogue is unchanged. Edge blocks dispatched first.
constexpr int TIR = 8;                  // interior rows per wave (Haar block)
constexpr int TIC = 48;                 // interior cols per block
constexpr int MR  = 12;                 // max rows/wave (block-edge waves)
constexpr int BRI = 32;                 // interior rows per block
constexpr int BROWSB = WID / BRI;       // 10 block-rows
constexpr int BCOLSB = 7;               // ceil(320/48), last interior 32
constexpr int BPS = BROWSB * BCOLSB;    // 70 blocks per slice
constexpr int NEDGEB = 2 * BCOLSB + 2 * (BROWSB - 2);   // 30 edge blocks/slice

template<bool EDGE>
__device__ __forceinline__ void tv_core_cw(const float* __restrict__ g,
        int gi0, int gj, int wv, bool nr12, bool hasUp, bool hasDn, bool w0,
        float (*xpy)[64], float (*xub)[64], int lane, float (&uf)[TIR]) {
    float z_[MR], px_[MR], py_[MR];
    const bool colin = !EDGE || ((unsigned)gj < (unsigned)WID);
#pragma unroll
    for (int r = 0; r < MR; r++) { z_[r] = 0.f; px_[r] = 0.f; py_[r] = 0.f; }
#pragma unroll
    for (int r = 0; r < TIR; r++) {
        int gi = gi0 + r;
        if (!EDGE) z_[r] = g[gi * WID + gj];
        else if (colin && ((unsigned)gi < (unsigned)WID)) z_[r] = g[gi * WID + gj];
    }
    if (nr12) {
#pragma unroll
        for (int r = TIR; r < MR; r++) {
            int gi = gi0 + r;
            if (!EDGE) z_[r] = g[gi * WID + gj];
            else if (colin && ((unsigned)gi < (unsigned)WID)) z_[r] = g[gi * WID + gj];
        }
    }
    const bool gj_le0 = EDGE && (gj <= 0);
    const bool gj_hi  = EDGE && (gj >= WID - 1);
    const bool gx_on  = !EDGE || (gj < WID - 1);
    const int  wup    = (wv > 0) ? wv - 1 : 0;
    const int  wdn    = (wv < 3) ? wv + 1 : 3;

#pragma clang loop unroll(disable)
    for (int it = 0; it < 5; it++) {
        float u_[MR], sh[MR];
        // ---- exchange py boundary (old p) downward ----
        xpy[wv][lane] = nr12 ? py_[MR - 1] : py_[TIR - 1];
        __syncthreads();
        const float pym_in = hasUp ? xpy[wup][lane] : 0.f;
        // batch shfl_up(px) (independent DS ops, R12 lesson)
#pragma unroll
        for (int r = 0; r < TIR; r++) sh[r] = __shfl_up(px_[r], 1);
        if (nr12) {
#pragma unroll
            for (int r = TIR; r < MR; r++) sh[r] = __shfl_up(px_[r], 1);
        }
        // u[r] = z[r] - lam*div(p)[r]  (old p; rows independent)
#pragma unroll
        for (int r = 0; r < TIR; r++) {
            float divx, divy;
            if (!EDGE) {
                divx = px_[r] - sh[r];
                divy = (r > 0) ? py_[r] - py_[r - 1]
                               : (hasUp ? py_[0] - pym_in : 0.f);  // wave0 r=0 halo
            } else {
                int gi = gi0 + r;
                divx = gj_le0 ? px_[r] : (gj_hi ? -sh[r] : px_[r] - sh[r]);
                float pym = (r > 0) ? py_[r - 1] : (hasUp ? pym_in : py_[0]);
                divy = (gi <= 0) ? py_[r]
                     : ((gi >= WID - 1) ? -pym : py_[r] - pym);
            }
            u_[r] = z_[r] - LAM_TV * (divx + divy);
        }
        if (nr12) {
#pragma unroll
            for (int r = TIR; r < MR; r++) {
                float divx, divy;
                if (!EDGE) {
                    divx = px_[r] - sh[r];
                    divy = py_[r] - py_[r - 1];
                } else {
                    int gi = gi0 + r;
                    divx = gj_le0 ? px_[r] : (gj_hi ? -sh[r] : px_[r] - sh[r]);
                    float pym = py_[r - 1];
                    divy = (gi <= 0) ? py_[r]
                         : ((gi >= WID - 1) ? -pym : py_[r] - pym);
                }
                u_[r] = z_[r] - LAM_TV * (divx + divy);
            }
        } else {
#pragma unroll
            for (int r = TIR; r < MR; r++) u_[r] = 0.f;
        }
        // ---- exchange u boundary (fresh u) upward ----
        xub[wv][lane] = u_[0];
        __syncthreads();
        const float ub_in = hasDn ? xub[wdn][lane] : 0.f;
        // batch shfl_down(u)
#pragma unroll
        for (int r = 0; r < TIR; r++) sh[r] = __shfl_down(u_[r], 1);
        if (nr12) {
#pragma unroll
            for (int r = TIR; r < MR; r++) sh[r] = __shfl_down(u_[r], 1);
        }
        // p[r] = proj(p[r] + tau*grad(u)[r])
#pragma unroll
        for (int r = 0; r < TIR; r++) {
            float ub = (r < TIR - 1) ? u_[r + 1] : (nr12 ? u_[TIR] : ub_in);
            float gx, gy;
            if (!EDGE) {
                gx = sh[r] - u_[r];
                gy = ub - u_[r];
            } else {
                int gi = gi0 + r;
                gx = gx_on ? sh[r] - u_[r] : 0.f;
                gy = (gi < WID - 1) ? ub - u_[r] : 0.f;
            }
            float px = fmaf(0.25f, gx, px_[r]);
            float py = fmaf(0.25f, gy, py_[r]);
            float n2 = fmaf(px, px, fmaf(py, py, 1e-8f));
            float inv = fminf(fast_rsq(n2), 1.f);
            px_[r] = px * inv;
            py_[r] = py * inv;
        }
        if (nr12) {
#pragma unroll
            for (int r = TIR; r < MR; r++) {
                bool vb = (r < MR - 1) || hasDn;      // wave3 r=11: bottom halo
                float ub = (r < MR - 1) ? u_[r + 1] : ub_in;
                float gx, gy;
                if (!EDGE) {
                    gx = sh[r] - u_[r];
                    gy = vb ? ub - u_[r] : 0.f;
                } else {
                    int gi = gi0 + r;
                    gx = gx_on ? sh[r] - u_[r] : 0.f;
                    gy = (gi < WID - 1 && vb) ? ub - u_[r] : 0.f;
                }
                float px = fmaf(0.25f, gx, px_[r]);
                float py = fmaf(0.25f, gy, py_[r]);
                float n2 = fmaf(px, px, fmaf(py, py, 1e-8f));
                float inv = fminf(fast_rsq(n2), 1.f);
                px_[r] = px * inv;
                py_[r] = py * inv;
            }
        }
    }
    // ---- final x_tv: one more py exchange, then interior rows only ----
    xpy[wv][lane] = nr12 ? py_[MR - 1] : py_[TIR - 1];
    __syncthreads();
    const float pym_in = hasUp ? xpy[wup][lane] : 0.f;
    float shf[MR], uff[MR];
#pragma unroll
    for (int r = 0; r < TIR; r++) shf[r] = __shfl_up(px_[r], 1);
    if (w0) {
#pragma unroll
        for (int r = TIR; r < MR; r++) shf[r] = __shfl_up(px_[r], 1);
    }
#pragma unroll
    for (int r = 0; r < TIR; r++) {
        float pxm = shf[r];
        float pyab = (r > 0) ? py_[r - 1] : pym_in;
        float divx, divy;
        if (!EDGE) {
            divx = px_[r] - pxm;
            divy = py_[r] - pyab;
        } else {
            int gi = gi0 + r;
            divx = gj_le0 ? px_[r] : (gj_hi ? -pxm : px_[r] - pxm);
            divy = (gi <= 0) ? py_[r]
                 : ((gi >= WID - 1) ? -pyab : py_[r] - pyab);
        }
        uff[r] = z_[r] - LAM_TV * (divx + divy);
    }
    if (w0) {
#pragma unroll
        for (int r = TIR; r < MR; r++) {
            float pxm = shf[r];
            float pyab = py_[r - 1];
            float divx, divy;
            if (!EDGE) {
                divx = px_[r] - pxm;
                divy = py_[r] - pyab;
            } else {
                int gi = gi0 + r;
                divx = gj_le0 ? px_[r] : (gj_hi ? -pxm : px_[r] - pxm);
                divy = (gi <= 0) ? py_[r]
                     : ((gi >= WID - 1) ? -pyab : py_[r] - pyab);
            }
            uff[r] = z_[r] - LAM_TV * (divx + divy);
        }
    } else {
#pragma unroll
        for (int r = TIR; r < MR; r++) uff[r] = 0.f;
    }
    // wave0's interior is rows 4..11; others rows 0..7 (compile-time select)
#pragma unroll
    for (int i = 0; i < TIR; i++) uf[i] = w0 ? uff[i + 4] : uff[i];
}

template<bool STOREZ>
__global__ __launch_bounds__(256) void tv_wav_fista(const float* __restrict__ zs,
                                                    float* __restrict__ x,
                                                    float* __restrict__ z,
                                                    float beta) {
    __shared__ float xpy[4][64];   // py boundary exchange (downward)
    __shared__ float xub[4][64];   // u boundary exchange (upward)
    const int lane = threadIdx.x & 63;
    const int wv   = __builtin_amdgcn_readfirstlane(threadIdx.x >> 6);
    const int b    = blockIdx.x;                    // 32*70 = 2240 blocks
    const int sl   = b / BPS;
    const int rem  = b - sl * BPS;
    // edge blocks first (rem < NEDGEB), interior after — tail shaping
    int brow, bcol;
    if (rem < 2 * BCOLSB) {                     // top & bottom block-rows
        brow = (rem < BCOLSB) ? 0 : (BROWSB - 1);
        bcol = (rem < BCOLSB) ? rem : rem - BCOLSB;
    } else if (rem < NEDGEB) {                  // left & right block-cols
        int e = rem - 2 * BCOLSB;               // 0..15
        brow = 1 + (e & 7);
        bcol = (e < 8) ? 0 : (BCOLSB - 1);
    } else {                                    // interior: 8 rows x 5 cols
        int i2 = rem - NEDGEB;
        brow = 1 + i2 / 5;
        bcol = 1 + i2 - 5 * (i2 / 5);
    }
    const int base = brow * BRI;
    const int gj   = bcol * TIC - 8 + lane;         // interior at lanes [8,56)
    const bool nr12  = (wv == 0) || (wv == 3);      // block-edge waves: 12 rows
    const bool hasUp = (wv != 0);
    const bool hasDn = (wv != 3);
    const bool w0    = (wv == 0);
    const int gi0  = base - 4 + ((wv == 0) ? 0 : 4 + 8 * wv);
    const float* g = zs + (size_t)sl * HWc;
    const bool edge = (brow == 0) || (brow == BROWSB - 1) ||
                      (bcol == 0) || (bcol == BCOLSB - 1);   // block-uniform

    float uf[TIR];
    if (!edge) tv_core_cw<false>(g, gi0, gj, wv, nr12, hasUp, hasDn, w0,
                                 xpy, xub, lane, uf);
    else       tv_core_cw<true >(g, gi0, gj, wv, nr12, hasUp, hasDn, w0,
                                 xpy, xub, lane, uf);

    // ---- 3-level Haar + soft-threshold (replicated-lane forward) ----
    const float sc1 = (lane & 1) ? -1.f : 1.f;
    const float sc2 = (lane & 2) ? -1.f : 1.f;
    const float sc3 = (lane & 4) ? -1.f : 1.f;

    float ll1[4], lh1[4], hl1[4], hh1[4];
#pragma unroll
    for (int k = 0; k < 4; k++) {
        float a0 = uf[2 * k], a1 = uf[2 * k + 1];
        float n0 = __shfl_xor(a0, 1), n1 = __shfl_xor(a1, 1);
        float h0 = a0 + n0, d0 = sc1 * (a0 - n0);   // replicated in both lanes
        float h1 = a1 + n1, d1 = sc1 * (a1 - n1);
        ll1[k] = (h0 + h1) * 0.5f;
        lh1[k] = softt((h0 - h1) * 0.5f);
        hl1[k] = softt((d0 + d1) * 0.5f);
        hh1[k] = softt((d0 - d1) * 0.5f);
    }
    float ll2[2], lh2[2], hl2[2], hh2[2];
#pragma unroll
    for (int k = 0; k < 2; k++) {
        float a0 = ll1[2 * k], a1 = ll1[2 * k + 1];
        float n0 = __shfl_xor(a0, 2), n1 = __shfl_xor(a1, 2);
        float h0 = a0 + n0, d0 = sc2 * (a0 - n0);
        float h1 = a1 + n1, d1 = sc2 * (a1 - n1);
        ll2[k] = (h0 + h1) * 0.5f;
        lh2[k] = softt((h0 - h1) * 0.5f);
        hl2[k] = softt((d0 + d1) * 0.5f);
        hh2[k] = softt((d0 - d1) * 0.5f);
    }
    float ll3, lh3, hl3, hh3;
    {
        float a0 = ll2[0], a1 = ll2[1];
        float n0 = __shfl_xor(a0, 4), n1 = __shfl_xor(a1, 4);
        float h0 = a0 + n0, d0 = sc3 * (a0 - n0);
        float h1 = a1 + n1, d1 = sc3 * (a1 - n1);
        ll3 = (h0 + h1) * 0.5f;
        lh3 = softt((h0 - h1) * 0.5f);
        hl3 = softt((d0 + d1) * 0.5f);
        hh3 = softt((d0 - d1) * 0.5f);
    }
    // ---- inverse (shuffle-free: values replicated within blocks) ----
    float l2p[2];
    l2p[0] = 0.5f * ((ll3 + lh3) + sc3 * (hl3 + hh3));
    l2p[1] = 0.5f * ((ll3 - lh3) + sc3 * (hl3 - hh3));
    float l1p[4];
#pragma unroll
    for (int k = 0; k < 2; k++) {
        l1p[2 * k]     = 0.5f * ((l2p[k] + lh2[k]) + sc2 * (hl2[k] + hh2[k]));
        l1p[2 * k + 1] = 0.5f * ((l2p[k] - lh2[k]) + sc2 * (hl2[k] - hh2[k]));
    }
    float xn[TIR];
#pragma unroll
    for (int k = 0; k < 4; k++) {
        xn[2 * k]     = 0.5f * ((l1p[k] + lh1[k]) + sc1 * (hl1[k] + hh1[k]));
        xn[2 * k + 1] = 0.5f * ((l1p[k] - lh1[k]) + sc1 * (hl1[k] - hh1[k]));
    }

    // ---- FISTA: z = xn + beta*(xn - x_old); x = xn ----
    const bool wcol = (lane >= 8) && (lane < 56) && ((unsigned)gj < (unsigned)WID);
    float* px = x + (size_t)sl * HWc;
    float* pz = z + (size_t)sl * HWc;
    const int gi_int0 = base + 8 * wv;
#pragma unroll
    for (int i = 0; i < TIR; i++) {
        int off = (gi_int0 + i) * WID + gj;
        if (STOREZ) {
            float xo = wcol ? px[off] : 0.f;
            float zn = xn[i] + beta * (xn[i] - xo);
            if (wcol) {
                px[off] = xn[i];
                pz[off] = zn;
            }
        } else {
            if (wcol) px[off] = xn[i];   // last iteration: only x needed
        }
    }
}

// ---------------- host orchestration ----------------
extern "C" void kernel_launch(void* const* d_in, const int* in_sizes, int n_in,
                              void* d_out, int out_size, void* d_ws, size_t ws_size,
                              hipStream_t stream) {
    const float* y    = (const float*)d_in[0];
    const float* mask = (const float*)d_in[1];
    float* x = (float*)d_out;

    float* ws = (float*)d_ws;
    float* z  = ws;                       // NTOT
    float* t1 = ws + (size_t)NTOT;        // NTOT
    float* t2 = ws + 2 * (size_t)NTOT;    // NTOT
    float* tw = ws + 3 * (size_t)NTOT;    // 2*14*64 floats twiddle tables
    float* twF = tw;                      // forward (SGN=-1)
    float* twI = tw + 14 * 64;            // inverse (SGN=+1)

    const int ROW_BLKS = (NIMG * 320) / 4;      // 1280 (1 line/wave)
    const int COL_BLKS = NIMG * (WID / CB);     // 640 (8 cols, 8 waves/block)
    const int TV_BLKS  = NSL * BPS;             // 2240 (4-wave coop blocks)

    build_tw<<<1, 64, 0, stream>>>(tw);

    // x0 = ifft2c(y): col-inverse then row-inverse (dual store -> x and z)
    fft_col<0><<<COL_BLKS, 512, 0, stream>>>(y, t1, nullptr, nullptr, twF);
    fft_row<1, 3><<<ROW_BLKS, 256, 0, stream>>>(t1, x, nullptr, z, twI);

    float t = 1.f;
    for (int it = 0; it < 15; it++) {
        // row-forward; fused (col-forward + DC + col-inverse); row-inverse
        // with residual epilogue: zs = z - g
        fft_row<-1, 0><<<ROW_BLKS, 256, 0, stream>>>(z, t1, nullptr, nullptr, twF);
        fft_col<1><<<COL_BLKS, 512, 0, stream>>>(t1, t2, y, mask, twF);
        fft_row<1, 2><<<ROW_BLKS, 256, 0, stream>>>(t2, t1, z, nullptr, twI);

        // TV prox + wavelet shrinkage + FISTA momentum, one kernel
        float tn   = (1.f + sqrtf(1.f + 4.f * t * t)) * 0.5f;
        float beta = (t - 1.f) / tn;
        t = tn;
        if (it < 14)
            tv_wav_fista<true ><<<TV_BLKS, 256, 0, stream>>>(t1, x, z, beta);
        else
            tv_wav_fista<false><<<TV_BLKS, 256, 0, stream>>>(t1, x, z, beta);
    }
    (void)in_sizes; (void)n_in; (void)out_size; (void)ws_size;
}